// Round 16
// baseline (106.585 us; speedup 1.0000x reference)
//
#include <hip/hip_runtime.h>
#include <hip/hip_bf16.h>

#define BB 2
#define CC 128
#define HH 48
#define WW 48
#define NN (HH*WW)          // 2304
#define PB 26               // 25 bins + spill (only ever gets +0.0)
#define HST 27              // private hist stride (odd -> bank spread)
#define QT 16               // queries per block
#define MT 64               // m per iteration
#define MSPLIT 2            // m-range split -> 576 blocks
#define NTILES (NN/QT)      // 144
#define ITERS (NN/MSPLIT/MT)  // 18
#define SLICE (QT*PB)       // 416 floats per partial slice
#define PSCALE 65536.0f
#define PINV   (1.0f/65536.0f)
#define FQ     262144.0f    // f-quantization scale (2^18; count<=72 needs 7b)
#define FQINV  (1.0f/262144.0f)

typedef __bf16 bf16x8 __attribute__((ext_vector_type(8)));
typedef float  f32x4  __attribute__((ext_vector_type(4)));
typedef unsigned int u32x4 __attribute__((ext_vector_type(4)));
typedef unsigned short u16;
typedef unsigned int   u32;

static __device__ __forceinline__ u16 f2bf(float x) {
    __hip_bfloat16 h = __float2bfloat16(x);
    return __builtin_bit_cast(u16, h);
}

// async global->LDS, 16B per lane, linear dest (base + lane*16)
static __device__ __forceinline__ void gload_lds16(const void* g, void* l) {
    __builtin_amdgcn_global_load_lds(
        (const __attribute__((address_space(1))) void*)g,
        (__attribute__((address_space(3))) void*)l, 16, 0, 0);
}

// Fused producer (r12 form): blocks [0,144) transpose img1 -> Qt[b][n][c];
// blocks [144,288) bilinear grid-sample img2 -> Dt[b][m][c]. Block 0 zeroes out.
__global__ __launch_bounds__(256)
void k_prep(const float* __restrict__ img1, const float* __restrict__ img2,
            const float* __restrict__ grid, u16* __restrict__ Qt,
            u16* __restrict__ Dt, float* __restrict__ out) {
    int blk = blockIdx.x;
    if (blk == 0 && threadIdx.x == 0) out[0] = 0.0f;
    bool isg = blk >= 144;
    int bb  = isg ? blk - 144 : blk;
    int bm  = (bb >> 3) * 256 + threadIdx.x;   // b*NN + n, 18*256 = 4608
    int cc0 = (bb & 7) * 16;
    int b   = bm / NN;
    int p   = bm - b * NN;
    u16 tmp[16];
    if (!isg) {
        const float* im = img1 + (size_t)b * CC * NN + (size_t)cc0 * NN;
        #pragma unroll
        for (int c = 0; c < 16; ++c) tmp[c] = f2bf(im[(size_t)c * NN + p]);
        uint4* dst = reinterpret_cast<uint4*>(Qt + (size_t)bm * CC + cc0);
        dst[0] = *reinterpret_cast<uint4*>(&tmp[0]);
        dst[1] = *reinterpret_cast<uint4*>(&tmp[8]);
    } else {
        float gx = grid[bm * 2 + 0];
        float gy = grid[bm * 2 + 1];
        float ix = ((gx + 1.0f) * (float)WW - 1.0f) * 0.5f;
        float iy = ((gy + 1.0f) * (float)HH - 1.0f) * 0.5f;
        float x0f = floorf(ix), y0f = floorf(iy);
        float wx1 = ix - x0f, wy1 = iy - y0f;
        float wx0 = 1.0f - wx1, wy0 = 1.0f - wy1;
        int x0 = (int)x0f, y0 = (int)y0f;
        bool xv0 = (x0 >= 0) && (x0 < WW);
        bool xv1 = (x0 + 1 >= 0) && (x0 + 1 < WW);
        bool yv0 = (y0 >= 0) && (y0 < HH);
        bool yv1 = (y0 + 1 >= 0) && (y0 + 1 < HH);
        int x0c = min(max(x0, 0), WW - 1), x1c = min(max(x0 + 1, 0), WW - 1);
        int y0c = min(max(y0, 0), HH - 1), y1c = min(max(y0 + 1, 0), HH - 1);
        float w00 = (xv0 && yv0) ? wx0 * wy0 : 0.0f;
        float w01 = (xv1 && yv0) ? wx1 * wy0 : 0.0f;
        float w10 = (xv0 && yv1) ? wx0 * wy1 : 0.0f;
        float w11 = (xv1 && yv1) ? wx1 * wy1 : 0.0f;
        int p00 = y0c * WW + x0c, p01 = y0c * WW + x1c;
        int p10 = y1c * WW + x0c, p11 = y1c * WW + x1c;
        const float* im = img2 + (size_t)b * CC * NN + (size_t)cc0 * NN;
        #pragma unroll
        for (int c = 0; c < 16; ++c) {
            const float* pl = im + (size_t)c * NN;
            tmp[c] = f2bf(pl[p00] * w00 + pl[p01] * w01 + pl[p10] * w10 + pl[p11] * w11);
        }
        uint4* dst = reinterpret_cast<uint4*>(Dt + (size_t)bm * CC + cc0);
        dst[0] = *reinterpret_cast<uint4*>(&tmp[0]);
        dst[1] = *reinterpret_cast<uint4*>(&tmp[8]);
    }
}

// main: r15 structure; SINGLE CHANGE: Ds is DOUBLE-BUFFERED and the loop has
// ONE barrier per iteration (was 2). Stage of tile it+1 is issued right after
// the barrier and stays in flight under the whole MFMA+hist phase; the next
// iteration's barrier (implicit vmcnt(0) drain) completes it. Ordering:
// readers of buf^1 finished before the barrier that precedes its overwrite.
// 18 barriers instead of 36; staging latency fully hidden. LDS 62.1 KB.
__global__ __launch_bounds__(256)
void k_main(const u16* __restrict__ Qt, const u16* __restrict__ Dt,
            float* __restrict__ Hall, float* __restrict__ Hpos) {
    __shared__ u16  Ds[2][MT * 128];    // 32768 B (swizzled 16B blocks, dbuf)
    __shared__ u32  priv[256 * HST];    // 27648 B  packed per-thread hist
    __shared__ u32  poshu[QT * PB];     //  1664 B  -> 62080 B total

    int tid  = threadIdx.x;
    int bidx = blockIdx.x;              // ((b*144 + ntile)*MSPLIT + ms)
    int b     = bidx / (NTILES * MSPLIT);
    int rem   = bidx % (NTILES * MSPLIT);
    int ntile = rem / MSPLIT;
    int ms    = rem % MSPLIT;
    int n0 = ntile * QT;

    {   // zero priv: 6912 u32 = 1728 uint4
        u32x4 z = {0u, 0u, 0u, 0u};
        u32x4* pv = reinterpret_cast<u32x4*>(priv);
        #pragma unroll
        for (int i = 0; i < 1728 / 256; ++i) pv[i * 256 + tid] = z;
        pv[1536 + (tid & 191)] = z;     // tail 192 (written twice by some, fine)
    }
    for (int i = tid; i < QT * PB; i += 256) poshu[i] = 0u;

    int lane = tid & 63, wave = tid >> 6, quad = lane >> 4, l15 = lane & 15;
    int q  = l15;                       // this lane's query, whole kernel
    int n  = n0 + q;
    int rn = n / WW, cn = n % WW;
    u32* ph = &priv[tid * HST];

    // Q fragments: loop-invariant, held in registers (coalesced global read)
    const u16* qrow = Qt + (size_t)(b * NN + n0 + l15) * CC + quad * 8;
    bf16x8 bv0 = *reinterpret_cast<const bf16x8*>(qrow);
    bf16x8 bv1 = *reinterpret_cast<const bf16x8*>(qrow + 32);
    bf16x8 bv2 = *reinterpret_cast<const bf16x8*>(qrow + 64);
    bf16x8 bv3 = *reinterpret_cast<const bf16x8*>(qrow + 96);

    int mstart = ms * (NN / MSPLIT);
    int mb0 = mstart + wave * 16 + quad * 4;  // this thread's first m
    int rm = mb0 / WW, cm = mb0 % WW;         // tracked incrementally (+64/iter)

    // Ds fragment row & swizzle key (constant per thread)
    int arow = wave * 16 + l15;
    int ak   = arow & 7;
    int wbase = tid & ~63;              // wave*64
    int srow[4], sgcol;                 // staging coords (constant per thread)
    sgcol = tid & 15;
    #pragma unroll
    for (int k = 0; k < 4; ++k) srow[k] = (tid + k * 256) >> 4;

    // prologue: stage tile 0 into buffer 0 (drained by first barrier)
    #pragma unroll
    for (int k = 0; k < 4; ++k) {
        int row  = srow[k];
        int gcol = sgcol ^ (row & 7);
        int r0   = (wbase + k * 256) >> 4;
        gload_lds16(Dt + ((size_t)(b * NN + mstart + row)) * CC + gcol * 8,
                    &Ds[0][r0 * 128]);
    }

    int cur = 0;
    for (int it = 0; it < ITERS; ++it) {
        __syncthreads();                // drains vmcnt -> Ds[cur] complete;
                                        // prev readers of Ds[cur^1] done
        if (it + 1 < ITERS) {           // stage next tile, in flight all iter
            int m0n = mstart + (it + 1) * MT;
            #pragma unroll
            for (int k = 0; k < 4; ++k) {
                int row  = srow[k];
                int gcol = sgcol ^ (row & 7);
                int r0   = (wbase + k * 256) >> 4;
                gload_lds16(Dt + ((size_t)(b * NN + m0n + row)) * CC + gcol * 8,
                            &Ds[cur ^ 1][r0 * 128]);
            }
        }

        f32x4 acc = {0.f, 0.f, 0.f, 0.f};
        {
            const u16* dbuf = Ds[cur];
            int j0 = (0 * 4 + quad) ^ ak;
            int j1 = (1 * 4 + quad) ^ ak;
            int j2 = (2 * 4 + quad) ^ ak;
            int j3 = (3 * 4 + quad) ^ ak;
            bf16x8 a0 = *reinterpret_cast<const bf16x8*>(&dbuf[arow * 128 + j0 * 8]);
            bf16x8 a1 = *reinterpret_cast<const bf16x8*>(&dbuf[arow * 128 + j1 * 8]);
            bf16x8 a2 = *reinterpret_cast<const bf16x8*>(&dbuf[arow * 128 + j2 * 8]);
            bf16x8 a3 = *reinterpret_cast<const bf16x8*>(&dbuf[arow * 128 + j3 * 8]);
            acc = __builtin_amdgcn_mfma_f32_16x16x32_bf16(a0, bv0, acc, 0, 0, 0);
            acc = __builtin_amdgcn_mfma_f32_16x16x32_bf16(a1, bv1, acc, 0, 0, 0);
            acc = __builtin_amdgcn_mfma_f32_16x16x32_bf16(a2, bv2, acc, 0, 0, 0);
            acc = __builtin_amdgcn_mfma_f32_16x16x32_bf16(a3, bv3, acc, 0, 0, 0);
        }

        #pragma unroll
        for (int i = 0; i < 4; ++i) {
            float s  = acc[i];
            float t  = fminf(fmaxf(fmaf(-12.0f, s, 12.0f), 0.0f), 24.0f);
            float cf = floorf(t);
            float f  = t - cf;
            int   c0 = (int)cf;               // [0,24]
            u32 pv = ph[c0];                  // packed: count<<25 | fsum(q18)
            ph[c0] = pv + 0x2000000u + (u32)(fmaf(f, FQ, 0.5f));
            int ci = cm + i, ri = rm;         // col may wrap once (i<=3)
            if (ci >= WW) { ci -= WW; ++ri; }
            int dr = rn - ri, dc = cn - ci;
            if ((unsigned)(dr + 4) <= 8u && (unsigned)(dc + 4) <= 8u) {
                u32 w0 = (u32)(fmaf(-PSCALE, f, PSCALE) + 0.5f);  // (1-f)*2^16
                u32 w1 = (u32)(f * PSCALE + 0.5f);
                atomicAdd(&poshu[q * PB + c0],     w0);   // native u32 LDS atomic
                atomicAdd(&poshu[q * PB + c0 + 1], w1);
            }
        }
        rm += 1; cm += 16;                    // m += 64 == +1 row +16 cols
        if (cm >= WW) { cm -= WW; ++rm; }
        cur ^= 1;
    }
    __syncthreads();
    // flush partial slices, [c][q] layout. Unpack: all[c] = cnt[c] - fs[c]/FQ
    // + fs[c-1]/FQ  (c==25 spill is always exactly 0: c0==24 implies f==0).
    float* oa = Hall + (size_t)bidx * SLICE;
    float* op = Hpos + (size_t)bidx * SLICE;
    for (int idx = tid; idx < SLICE; idx += 256) {
        int c = idx >> 4, qq = idx & 15;
        float allv;
        if (c >= 25) {
            allv = 0.0f;
        } else {
            u32 cnt = 0; float fs = 0.f, fsm = 0.f;
            #pragma unroll
            for (int j = 0; j < 16; ++j) {
                u32 v = priv[(j * 16 + qq) * HST + c];
                cnt += v >> 25; fs += (float)(v & 0x1FFFFFFu);
            }
            if (c > 0) {
                #pragma unroll
                for (int j = 0; j < 16; ++j)
                    fsm += (float)(priv[(j * 16 + qq) * HST + c - 1] & 0x1FFFFFFu);
            }
            allv = (float)cnt - fs * FQINV + fsm * FQINV;
        }
        oa[idx] = allv;
        op[idx] = (float)poshu[qq * PB + c] * PINV;
    }
}

// AP from MSPLIT partial hists + reliability + mean -> scalar (r12 form)
__global__ __launch_bounds__(256)
void k_finalize(const float* __restrict__ Hall, const float* __restrict__ Hpos,
                const float* __restrict__ rel, float* __restrict__ out) {
    int gid = blockIdx.x * 256 + threadIdx.x;   // 0..4607
    int b = gid / NN, nloc = gid % NN;
    int ntile = nloc >> 4, qq = nloc & 15;
    size_t base = ((size_t)(b * NTILES + ntile) * MSPLIT) * SLICE + qq;
    const float* ha = Hall + base;
    const float* hp = Hpos + base;
    float cumr = 0.f, cumn = 0.f, apn = 0.f, totr = 0.f;
    #pragma unroll
    for (int c = 0; c < 25; ++c) {
        float a = 0.f, r = 0.f;
        #pragma unroll
        for (int s = 0; s < MSPLIT; ++s) {
            a += ha[(size_t)s * SLICE + c * 16];
            r += hp[(size_t)s * SLICE + c * 16];
        }
        cumr += r; cumn += a;
        apn  += (cumr / (1e-16f + cumn)) * r;
        totr += r;
    }
    float ap = apn / totr;                      // totr >= 1 (self-match)
    float rl = rel[gid];
    float loss = 1.0f - (ap * rl + 0.5f * (1.0f - rl));

    for (int off = 32; off > 0; off >>= 1) loss += __shfl_down(loss, off, 64);
    __shared__ float wsum[4];
    int ln = threadIdx.x & 63, wv = threadIdx.x >> 6;
    if (ln == 0) wsum[wv] = loss;
    __syncthreads();
    if (threadIdx.x == 0) {
        float t = wsum[0] + wsum[1] + wsum[2] + wsum[3];
        atomicAdd(out, t * (1.0f / (float)(BB * NN)));
    }
}

extern "C" void kernel_launch(void* const* d_in, const int* in_sizes, int n_in,
                              void* d_out, int out_size, void* d_ws, size_t ws_size,
                              hipStream_t stream) {
    const float* img1 = (const float*)d_in[0];
    const float* img2 = (const float*)d_in[1];
    const float* rel  = (const float*)d_in[2];
    const float* grid = (const float*)d_in[3];

    char* ws = (char*)d_ws;
    const size_t qt_bytes   = (size_t)BB * NN * CC * sizeof(u16);                    // 1.18 MB
    const size_t part_bytes = (size_t)BB * NTILES * MSPLIT * SLICE * sizeof(float);  // 0.96 MB
    u16*   Qt   = (u16*)ws;
    u16*   Dt   = (u16*)(ws + qt_bytes);
    float* Hall = (float*)(ws + 2 * qt_bytes);
    float* Hpos = (float*)(ws + 2 * qt_bytes + part_bytes);

    k_prep    <<<288, 256, 0, stream>>>(img1, img2, grid, Qt, Dt, (float*)d_out);
    k_main    <<<BB * NTILES * MSPLIT, 256, 0, stream>>>(Qt, Dt, Hall, Hpos);
    k_finalize<<<(BB * NN) / 256, 256, 0, stream>>>(Hall, Hpos, rel, (float*)d_out);
}

// Round 17
// 94.586 us; speedup vs baseline: 1.1269x; 1.1269x over previous
//
#include <hip/hip_runtime.h>
#include <hip/hip_bf16.h>

#define BB 2
#define CC 128
#define HH 48
#define WW 48
#define NN (HH*WW)          // 2304
#define PB 26               // 25 bins + spill (only ever gets +0.0)
#define HST 27              // private hist stride (odd -> bank spread)
#define QT 16               // queries per block
#define MT 64               // m per iteration
#define MSPLIT 2            // m-range split -> 576 blocks
#define NTILES (NN/QT)      // 144
#define ITERS (NN/MSPLIT/MT)  // 18
#define SLICE (QT*PB)       // 416 floats per partial slice
#define PSCALE 65536.0f
#define PINV   (1.0f/65536.0f)
#define FQ     8192.0f      // f-quantization scale (2^13)
#define FQINV  (1.0f/8192.0f)

typedef __bf16 bf16x8 __attribute__((ext_vector_type(8)));
typedef float  f32x4  __attribute__((ext_vector_type(4)));
typedef unsigned int u32x4 __attribute__((ext_vector_type(4)));
typedef unsigned short u16;
typedef unsigned int   u32;

static __device__ __forceinline__ u16 f2bf(float x) {
    __hip_bfloat16 h = __float2bfloat16(x);
    return __builtin_bit_cast(u16, h);
}

// async global->LDS, 16B per lane, linear dest (base + lane*16)
static __device__ __forceinline__ void gload_lds16(const void* g, void* l) {
    __builtin_amdgcn_global_load_lds(
        (const __attribute__((address_space(1))) void*)g,
        (__attribute__((address_space(3))) void*)l, 16, 0, 0);
}

// Fused producer: blocks [0,144) transpose img1 -> Qt[b][n][c]; blocks
// [144,288) bilinear grid-sample img2 -> Dt[b][m][c]. Block 0 zeroes d_out.
__global__ __launch_bounds__(256)
void k_prep(const float* __restrict__ img1, const float* __restrict__ img2,
            const float* __restrict__ grid, u16* __restrict__ Qt,
            u16* __restrict__ Dt, float* __restrict__ out) {
    int blk = blockIdx.x;
    if (blk == 0 && threadIdx.x == 0) out[0] = 0.0f;
    bool isg = blk >= 144;
    int bb  = isg ? blk - 144 : blk;
    int bm  = (bb >> 3) * 256 + threadIdx.x;   // b*NN + n, 18*256 = 4608
    int cc0 = (bb & 7) * 16;
    int b   = bm / NN;
    int p   = bm - b * NN;
    u16 tmp[16];
    if (!isg) {
        const float* im = img1 + (size_t)b * CC * NN + (size_t)cc0 * NN;
        #pragma unroll
        for (int c = 0; c < 16; ++c) tmp[c] = f2bf(im[(size_t)c * NN + p]);
        uint4* dst = reinterpret_cast<uint4*>(Qt + (size_t)bm * CC + cc0);
        dst[0] = *reinterpret_cast<uint4*>(&tmp[0]);
        dst[1] = *reinterpret_cast<uint4*>(&tmp[8]);
    } else {
        float gx = grid[bm * 2 + 0];
        float gy = grid[bm * 2 + 1];
        float ix = ((gx + 1.0f) * (float)WW - 1.0f) * 0.5f;
        float iy = ((gy + 1.0f) * (float)HH - 1.0f) * 0.5f;
        float x0f = floorf(ix), y0f = floorf(iy);
        float wx1 = ix - x0f, wy1 = iy - y0f;
        float wx0 = 1.0f - wx1, wy0 = 1.0f - wy1;
        int x0 = (int)x0f, y0 = (int)y0f;
        bool xv0 = (x0 >= 0) && (x0 < WW);
        bool xv1 = (x0 + 1 >= 0) && (x0 + 1 < WW);
        bool yv0 = (y0 >= 0) && (y0 < HH);
        bool yv1 = (y0 + 1 >= 0) && (y0 + 1 < HH);
        int x0c = min(max(x0, 0), WW - 1), x1c = min(max(x0 + 1, 0), WW - 1);
        int y0c = min(max(y0, 0), HH - 1), y1c = min(max(y0 + 1, 0), HH - 1);
        float w00 = (xv0 && yv0) ? wx0 * wy0 : 0.0f;
        float w01 = (xv1 && yv0) ? wx1 * wy0 : 0.0f;
        float w10 = (xv0 && yv1) ? wx0 * wy1 : 0.0f;
        float w11 = (xv1 && yv1) ? wx1 * wy1 : 0.0f;
        int p00 = y0c * WW + x0c, p01 = y0c * WW + x1c;
        int p10 = y1c * WW + x0c, p11 = y1c * WW + x1c;
        const float* im = img2 + (size_t)b * CC * NN + (size_t)cc0 * NN;
        #pragma unroll
        for (int c = 0; c < 16; ++c) {
            const float* pl = im + (size_t)c * NN;
            tmp[c] = f2bf(pl[p00] * w00 + pl[p01] * w01 + pl[p10] * w10 + pl[p11] * w11);
        }
        uint4* dst = reinterpret_cast<uint4*>(Dt + (size_t)bm * CC + cc0);
        dst[0] = *reinterpret_cast<uint4*>(&tmp[0]);
        dst[1] = *reinterpret_cast<uint4*>(&tmp[8]);
    }
}

// main (best-measured r14 form): MSPLIT=2, async global_load_lds staging with
// inverse-swizzled source, register Q-frags, PACKED u32 per-thread hist --
// count in bits [20:31], fsum (f quantized at 2^13) in bits [0:19]; one
// ds_read + one ds_write per element. Positives via u32 LDS atomics.
// Reconstruction in flush: all[c] = count[c] - fsum[c]/8192 + fsum[c-1]/8192.
// Overflow: per-thread cell <= 72 elems -> count <= 72, fsum <= 589824 < 2^20.
__global__ __launch_bounds__(256)
void k_main(const u16* __restrict__ Qt, const u16* __restrict__ Dt,
            float* __restrict__ Hall, float* __restrict__ Hpos) {
    __shared__ u16  Ds[MT * 128];       // 16384 B (swizzled 16B blocks)
    __shared__ u32  priv[256 * HST];    // 27648 B  packed per-thread hist
    __shared__ u32  poshu[QT * PB];     //  1664 B  -> 45696 B total

    int tid  = threadIdx.x;
    int bidx = blockIdx.x;              // ((b*144 + ntile)*MSPLIT + ms)
    int b     = bidx / (NTILES * MSPLIT);
    int rem   = bidx % (NTILES * MSPLIT);
    int ntile = rem / MSPLIT;
    int ms    = rem % MSPLIT;
    int n0 = ntile * QT;

    {   // zero priv: 6912 u32 = 1728 uint4
        u32x4 z = {0u, 0u, 0u, 0u};
        u32x4* pv = reinterpret_cast<u32x4*>(priv);
        #pragma unroll
        for (int i = 0; i < 1728 / 256; ++i) pv[i * 256 + tid] = z;
        pv[1536 + (tid & 191)] = z;     // tail 192 (written twice by some, fine)
    }
    for (int i = tid; i < QT * PB; i += 256) poshu[i] = 0u;

    int lane = tid & 63, wave = tid >> 6, quad = lane >> 4, l15 = lane & 15;
    int q  = l15;                       // this lane's query, whole kernel
    int n  = n0 + q;
    int rn = n / WW, cn = n % WW;
    u32* ph = &priv[tid * HST];

    // Q fragments: loop-invariant, held in registers (coalesced global read)
    const u16* qrow = Qt + (size_t)(b * NN + n0 + l15) * CC + quad * 8;
    bf16x8 bv0 = *reinterpret_cast<const bf16x8*>(qrow);
    bf16x8 bv1 = *reinterpret_cast<const bf16x8*>(qrow + 32);
    bf16x8 bv2 = *reinterpret_cast<const bf16x8*>(qrow + 64);
    bf16x8 bv3 = *reinterpret_cast<const bf16x8*>(qrow + 96);

    int mstart = ms * (NN / MSPLIT);
    int mb0 = mstart + wave * 16 + quad * 4;  // this thread's first m
    int rm = mb0 / WW, cm = mb0 % WW;         // tracked incrementally (+64/iter)

    // Ds fragment row & swizzle key (constant per thread)
    int arow = wave * 16 + l15;
    int ak   = arow & 7;
    int wbase = tid & ~63;              // wave*64

    for (int it = 0; it < ITERS; ++it) {
        int m0 = mstart + it * MT;
        __syncthreads();
        #pragma unroll
        for (int k = 0; k < 4; ++k) {   // async stage: linear dest, pre-swz src
            int idx  = tid + k * 256;
            int row  = idx >> 4;                    // 0..63
            int gcol = (tid & 15) ^ (row & 7);      // inverse swizzle
            int r0   = (wbase + k * 256) >> 4;      // wave-uniform dest row
            gload_lds16(Dt + ((size_t)(b * NN + m0 + row)) * CC + gcol * 8,
                        &Ds[r0 * 128]);
        }
        __syncthreads();                // drains vmcnt(0) -> tile visible

        f32x4 acc = {0.f, 0.f, 0.f, 0.f};
        {
            int j0 = (0 * 4 + quad) ^ ak;
            int j1 = (1 * 4 + quad) ^ ak;
            int j2 = (2 * 4 + quad) ^ ak;
            int j3 = (3 * 4 + quad) ^ ak;
            bf16x8 a0 = *reinterpret_cast<const bf16x8*>(&Ds[arow * 128 + j0 * 8]);
            bf16x8 a1 = *reinterpret_cast<const bf16x8*>(&Ds[arow * 128 + j1 * 8]);
            bf16x8 a2 = *reinterpret_cast<const bf16x8*>(&Ds[arow * 128 + j2 * 8]);
            bf16x8 a3 = *reinterpret_cast<const bf16x8*>(&Ds[arow * 128 + j3 * 8]);
            acc = __builtin_amdgcn_mfma_f32_16x16x32_bf16(a0, bv0, acc, 0, 0, 0);
            acc = __builtin_amdgcn_mfma_f32_16x16x32_bf16(a1, bv1, acc, 0, 0, 0);
            acc = __builtin_amdgcn_mfma_f32_16x16x32_bf16(a2, bv2, acc, 0, 0, 0);
            acc = __builtin_amdgcn_mfma_f32_16x16x32_bf16(a3, bv3, acc, 0, 0, 0);
        }

        #pragma unroll
        for (int i = 0; i < 4; ++i) {
            float s  = acc[i];
            float t  = fminf(fmaxf(fmaf(-12.0f, s, 12.0f), 0.0f), 24.0f);
            float cf = floorf(t);
            float f  = t - cf;
            int   c0 = (int)cf;               // [0,24]
            u32 pv = ph[c0];                  // packed: count<<20 | fsum(q13)
            ph[c0] = pv + 0x100000u + (u32)(fmaf(f, FQ, 0.5f));
            int ci = cm + i, ri = rm;         // col may wrap once (i<=3)
            if (ci >= WW) { ci -= WW; ++ri; }
            int dr = rn - ri, dc = cn - ci;
            if ((unsigned)(dr + 4) <= 8u && (unsigned)(dc + 4) <= 8u) {
                u32 w0 = (u32)(fmaf(-PSCALE, f, PSCALE) + 0.5f);  // (1-f)*2^16
                u32 w1 = (u32)(f * PSCALE + 0.5f);
                atomicAdd(&poshu[q * PB + c0],     w0);   // native u32 LDS atomic
                atomicAdd(&poshu[q * PB + c0 + 1], w1);
            }
        }
        rm += 1; cm += 16;                    // m += 64 == +1 row +16 cols
        if (cm >= WW) { cm -= WW; ++rm; }
    }
    __syncthreads();
    // flush partial slices, [c][q] layout. Unpack: all[c] = cnt[c] - fs[c]/FQ
    // + fs[c-1]/FQ  (c==25 spill is always exactly 0: c0==24 implies f==0).
    float* oa = Hall + (size_t)bidx * SLICE;
    float* op = Hpos + (size_t)bidx * SLICE;
    for (int idx = tid; idx < SLICE; idx += 256) {
        int c = idx >> 4, qq = idx & 15;
        float allv;
        if (c >= 25) {
            allv = 0.0f;
        } else {
            u32 cnt = 0, fs = 0, fsm = 0;
            #pragma unroll
            for (int j = 0; j < 16; ++j) {
                u32 v = priv[(j * 16 + qq) * HST + c];
                cnt += v >> 20; fs += v & 0xFFFFFu;
            }
            if (c > 0) {
                #pragma unroll
                for (int j = 0; j < 16; ++j)
                    fsm += priv[(j * 16 + qq) * HST + c - 1] & 0xFFFFFu;
            }
            allv = (float)cnt - (float)fs * FQINV + (float)fsm * FQINV;
        }
        oa[idx] = allv;
        op[idx] = (float)poshu[qq * PB + c] * PINV;
    }
}

// AP from MSPLIT partial hists + reliability + mean -> scalar
__global__ __launch_bounds__(256)
void k_finalize(const float* __restrict__ Hall, const float* __restrict__ Hpos,
                const float* __restrict__ rel, float* __restrict__ out) {
    int gid = blockIdx.x * 256 + threadIdx.x;   // 0..4607
    int b = gid / NN, nloc = gid % NN;
    int ntile = nloc >> 4, qq = nloc & 15;
    size_t base = ((size_t)(b * NTILES + ntile) * MSPLIT) * SLICE + qq;
    const float* ha = Hall + base;
    const float* hp = Hpos + base;
    float cumr = 0.f, cumn = 0.f, apn = 0.f, totr = 0.f;
    #pragma unroll
    for (int c = 0; c < 25; ++c) {
        float a = 0.f, r = 0.f;
        #pragma unroll
        for (int s = 0; s < MSPLIT; ++s) {
            a += ha[(size_t)s * SLICE + c * 16];
            r += hp[(size_t)s * SLICE + c * 16];
        }
        cumr += r; cumn += a;
        apn  += (cumr / (1e-16f + cumn)) * r;
        totr += r;
    }
    float ap = apn / totr;                      // totr >= 1 (self-match)
    float rl = rel[gid];
    float loss = 1.0f - (ap * rl + 0.5f * (1.0f - rl));

    for (int off = 32; off > 0; off >>= 1) loss += __shfl_down(loss, off, 64);
    __shared__ float wsum[4];
    int ln = threadIdx.x & 63, wv = threadIdx.x >> 6;
    if (ln == 0) wsum[wv] = loss;
    __syncthreads();
    if (threadIdx.x == 0) {
        float t = wsum[0] + wsum[1] + wsum[2] + wsum[3];
        atomicAdd(out, t * (1.0f / (float)(BB * NN)));
    }
}

extern "C" void kernel_launch(void* const* d_in, const int* in_sizes, int n_in,
                              void* d_out, int out_size, void* d_ws, size_t ws_size,
                              hipStream_t stream) {
    const float* img1 = (const float*)d_in[0];
    const float* img2 = (const float*)d_in[1];
    const float* rel  = (const float*)d_in[2];
    const float* grid = (const float*)d_in[3];

    char* ws = (char*)d_ws;
    const size_t qt_bytes   = (size_t)BB * NN * CC * sizeof(u16);                    // 1.18 MB
    const size_t part_bytes = (size_t)BB * NTILES * MSPLIT * SLICE * sizeof(float);  // 0.96 MB
    u16*   Qt   = (u16*)ws;
    u16*   Dt   = (u16*)(ws + qt_bytes);
    float* Hall = (float*)(ws + 2 * qt_bytes);
    float* Hpos = (float*)(ws + 2 * qt_bytes + part_bytes);

    k_prep    <<<288, 256, 0, stream>>>(img1, img2, grid, Qt, Dt, (float*)d_out);
    k_main    <<<BB * NTILES * MSPLIT, 256, 0, stream>>>(Qt, Dt, Hall, Hpos);
    k_finalize<<<(BB * NN) / 256, 256, 0, stream>>>(Hall, Hpos, rel, (float*)d_out);
}

// Round 18
// 93.577 us; speedup vs baseline: 1.1390x; 1.0108x over previous
//
#include <hip/hip_runtime.h>
#include <hip/hip_bf16.h>

#define BB 2
#define CC 128
#define HH 48
#define WW 48
#define NN (HH*WW)          // 2304
#define PB 26               // 25 bins + spill (only ever gets +0.0)
#define HST 27              // private hist stride (odd -> bank spread)
#define QT 16               // queries per block
#define MT 64               // m per iteration
#define MSPLIT 2            // m-range split -> 576 blocks
#define NTILES (NN/QT)      // 144
#define ITERS (NN/MSPLIT/MT)  // 18
#define SLICE (QT*PB)       // 416 floats per partial slice
#define PSCALE 65536.0f
#define PINV   (1.0f/65536.0f)

typedef __bf16 bf16x8 __attribute__((ext_vector_type(8)));
typedef float  f32x4  __attribute__((ext_vector_type(4)));
typedef unsigned short u16;
typedef unsigned int   u32;

static __device__ __forceinline__ u16 f2bf(float x) {
    __hip_bfloat16 h = __float2bfloat16(x);
    return __builtin_bit_cast(u16, h);
}

// async global->LDS, 16B per lane, linear dest (base + lane*16)
static __device__ __forceinline__ void gload_lds16(const void* g, void* l) {
    __builtin_amdgcn_global_load_lds(
        (const __attribute__((address_space(1))) void*)g,
        (__attribute__((address_space(3))) void*)l, 16, 0, 0);
}

// Fused producer: blocks [0,144) transpose img1 -> Qt[b][n][c]; blocks
// [144,288) bilinear grid-sample img2 -> Dt[b][m][c]. Block 0 zeroes d_out.
__global__ __launch_bounds__(256)
void k_prep(const float* __restrict__ img1, const float* __restrict__ img2,
            const float* __restrict__ grid, u16* __restrict__ Qt,
            u16* __restrict__ Dt, float* __restrict__ out) {
    int blk = blockIdx.x;
    if (blk == 0 && threadIdx.x == 0) out[0] = 0.0f;
    bool isg = blk >= 144;
    int bb  = isg ? blk - 144 : blk;
    int bm  = (bb >> 3) * 256 + threadIdx.x;   // b*NN + n, 18*256 = 4608
    int cc0 = (bb & 7) * 16;
    int b   = bm / NN;
    int p   = bm - b * NN;
    u16 tmp[16];
    if (!isg) {
        const float* im = img1 + (size_t)b * CC * NN + (size_t)cc0 * NN;
        #pragma unroll
        for (int c = 0; c < 16; ++c) tmp[c] = f2bf(im[(size_t)c * NN + p]);
        uint4* dst = reinterpret_cast<uint4*>(Qt + (size_t)bm * CC + cc0);
        dst[0] = *reinterpret_cast<uint4*>(&tmp[0]);
        dst[1] = *reinterpret_cast<uint4*>(&tmp[8]);
    } else {
        float gx = grid[bm * 2 + 0];
        float gy = grid[bm * 2 + 1];
        float ix = ((gx + 1.0f) * (float)WW - 1.0f) * 0.5f;
        float iy = ((gy + 1.0f) * (float)HH - 1.0f) * 0.5f;
        float x0f = floorf(ix), y0f = floorf(iy);
        float wx1 = ix - x0f, wy1 = iy - y0f;
        float wx0 = 1.0f - wx1, wy0 = 1.0f - wy1;
        int x0 = (int)x0f, y0 = (int)y0f;
        bool xv0 = (x0 >= 0) && (x0 < WW);
        bool xv1 = (x0 + 1 >= 0) && (x0 + 1 < WW);
        bool yv0 = (y0 >= 0) && (y0 < HH);
        bool yv1 = (y0 + 1 >= 0) && (y0 + 1 < HH);
        int x0c = min(max(x0, 0), WW - 1), x1c = min(max(x0 + 1, 0), WW - 1);
        int y0c = min(max(y0, 0), HH - 1), y1c = min(max(y0 + 1, 0), HH - 1);
        float w00 = (xv0 && yv0) ? wx0 * wy0 : 0.0f;
        float w01 = (xv1 && yv0) ? wx1 * wy0 : 0.0f;
        float w10 = (xv0 && yv1) ? wx0 * wy1 : 0.0f;
        float w11 = (xv1 && yv1) ? wx1 * wy1 : 0.0f;
        int p00 = y0c * WW + x0c, p01 = y0c * WW + x1c;
        int p10 = y1c * WW + x0c, p11 = y1c * WW + x1c;
        const float* im = img2 + (size_t)b * CC * NN + (size_t)cc0 * NN;
        #pragma unroll
        for (int c = 0; c < 16; ++c) {
            const float* pl = im + (size_t)c * NN;
            tmp[c] = f2bf(pl[p00] * w00 + pl[p01] * w01 + pl[p10] * w10 + pl[p11] * w11);
        }
        uint4* dst = reinterpret_cast<uint4*>(Dt + (size_t)bm * CC + cc0);
        dst[0] = *reinterpret_cast<uint4*>(&tmp[0]);
        dst[1] = *reinterpret_cast<uint4*>(&tmp[8]);
    }
}

// main (best VERIFIED form, r12): MSPLIT=2, async global_load_lds staging
// with inverse-swizzled per-lane global source (linear LDS dest, same
// involution on the read side), loop-invariant Q fragments in registers,
// EXACT f32 per-thread private hist with plain ds RMW (absmax 0.0 on every
// run -- packed-u32 variant traded determinism for a noise-level gain and
// was rejected), u32 fixed-point LDS atomics for the rare positives.
__global__ __launch_bounds__(256)
void k_main(const u16* __restrict__ Qt, const u16* __restrict__ Dt,
            float* __restrict__ Hall, float* __restrict__ Hpos) {
    __shared__ u16  Ds[MT * 128];       // 16384 B (swizzled 16B blocks)
    __shared__ float priv[256 * HST];   // 27648 B  per-thread hist
    __shared__ u32   poshu[QT * PB];    //  1664 B  -> 45696 B total

    int tid  = threadIdx.x;
    int bidx = blockIdx.x;              // ((b*144 + ntile)*MSPLIT + ms)
    int b     = bidx / (NTILES * MSPLIT);
    int rem   = bidx % (NTILES * MSPLIT);
    int ntile = rem / MSPLIT;
    int ms    = rem % MSPLIT;
    int n0 = ntile * QT;

    {   // zero priv: 6912 floats = 1728 float4
        f32x4 z = {0.f, 0.f, 0.f, 0.f};
        f32x4* pv = reinterpret_cast<f32x4*>(priv);
        #pragma unroll
        for (int i = 0; i < 1728 / 256; ++i) pv[i * 256 + tid] = z;
        pv[1536 + (tid & 191)] = z;     // tail 192 (written twice by some, fine)
    }
    for (int i = tid; i < QT * PB; i += 256) poshu[i] = 0u;

    int lane = tid & 63, wave = tid >> 6, quad = lane >> 4, l15 = lane & 15;
    int q  = l15;                       // this lane's query, whole kernel
    int n  = n0 + q;
    int rn = n / WW, cn = n % WW;
    float* ph = &priv[tid * HST];

    // Q fragments: loop-invariant, held in registers (coalesced global read)
    const u16* qrow = Qt + (size_t)(b * NN + n0 + l15) * CC + quad * 8;
    bf16x8 bv0 = *reinterpret_cast<const bf16x8*>(qrow);
    bf16x8 bv1 = *reinterpret_cast<const bf16x8*>(qrow + 32);
    bf16x8 bv2 = *reinterpret_cast<const bf16x8*>(qrow + 64);
    bf16x8 bv3 = *reinterpret_cast<const bf16x8*>(qrow + 96);

    int mstart = ms * (NN / MSPLIT);
    int mb0 = mstart + wave * 16 + quad * 4;  // this thread's first m
    int rm = mb0 / WW, cm = mb0 % WW;         // tracked incrementally (+64/iter)

    // Ds fragment row & swizzle key (constant per thread)
    int arow = wave * 16 + l15;
    int ak   = arow & 7;
    int wbase = tid & ~63;              // wave*64

    for (int it = 0; it < ITERS; ++it) {
        int m0 = mstart + it * MT;
        __syncthreads();
        #pragma unroll
        for (int k = 0; k < 4; ++k) {   // async stage: linear dest, pre-swz src
            int idx  = tid + k * 256;
            int row  = idx >> 4;                    // 0..63
            int gcol = (tid & 15) ^ (row & 7);      // inverse swizzle
            int r0   = (wbase + k * 256) >> 4;      // wave-uniform dest row
            gload_lds16(Dt + ((size_t)(b * NN + m0 + row)) * CC + gcol * 8,
                        &Ds[r0 * 128]);
        }
        __syncthreads();                // drains vmcnt(0) -> tile visible

        f32x4 acc = {0.f, 0.f, 0.f, 0.f};
        {
            int j0 = (0 * 4 + quad) ^ ak;
            int j1 = (1 * 4 + quad) ^ ak;
            int j2 = (2 * 4 + quad) ^ ak;
            int j3 = (3 * 4 + quad) ^ ak;
            bf16x8 a0 = *reinterpret_cast<const bf16x8*>(&Ds[arow * 128 + j0 * 8]);
            bf16x8 a1 = *reinterpret_cast<const bf16x8*>(&Ds[arow * 128 + j1 * 8]);
            bf16x8 a2 = *reinterpret_cast<const bf16x8*>(&Ds[arow * 128 + j2 * 8]);
            bf16x8 a3 = *reinterpret_cast<const bf16x8*>(&Ds[arow * 128 + j3 * 8]);
            acc = __builtin_amdgcn_mfma_f32_16x16x32_bf16(a0, bv0, acc, 0, 0, 0);
            acc = __builtin_amdgcn_mfma_f32_16x16x32_bf16(a1, bv1, acc, 0, 0, 0);
            acc = __builtin_amdgcn_mfma_f32_16x16x32_bf16(a2, bv2, acc, 0, 0, 0);
            acc = __builtin_amdgcn_mfma_f32_16x16x32_bf16(a3, bv3, acc, 0, 0, 0);
        }

        #pragma unroll
        for (int i = 0; i < 4; ++i) {
            float s  = acc[i];
            float t  = fminf(fmaxf(fmaf(-12.0f, s, 12.0f), 0.0f), 24.0f);
            float cf = floorf(t);
            float f  = t - cf;
            int   c0 = (int)cf;               // [0,24]; c0==24 -> f==0 -> spill +0
            float h0 = ph[c0], h1 = ph[c0 + 1];
            ph[c0]     = h0 + (1.0f - f);     // plain ds RMW, private -> race-free
            ph[c0 + 1] = h1 + f;
            int ci = cm + i, ri = rm;         // col may wrap once (i<=3)
            if (ci >= WW) { ci -= WW; ++ri; }
            int dr = rn - ri, dc = cn - ci;
            if ((unsigned)(dr + 4) <= 8u && (unsigned)(dc + 4) <= 8u) {
                u32 w0 = (u32)(fmaf(-PSCALE, f, PSCALE) + 0.5f);  // (1-f)*2^16
                u32 w1 = (u32)(f * PSCALE + 0.5f);
                atomicAdd(&poshu[q * PB + c0],     w0);   // native u32 LDS atomic
                atomicAdd(&poshu[q * PB + c0 + 1], w1);
            }
        }
        rm += 1; cm += 16;                    // m += 64 == +1 row +16 cols
        if (cm >= WW) { cm -= WW; ++rm; }
    }
    __syncthreads();
    // flush partial slices, [c][q] layout (coalesced both sides)
    float* oa = Hall + (size_t)bidx * SLICE;
    float* op = Hpos + (size_t)bidx * SLICE;
    for (int idx = tid; idx < SLICE; idx += 256) {
        int c = idx >> 4, qq = idx & 15;
        float s2 = 0.0f;
        #pragma unroll
        for (int j = 0; j < 16; ++j) s2 += priv[(j * 16 + qq) * HST + c];
        oa[idx] = s2;
        op[idx] = (float)poshu[qq * PB + c] * PINV;
    }
}

// AP from MSPLIT partial hists + reliability + mean -> scalar
__global__ __launch_bounds__(256)
void k_finalize(const float* __restrict__ Hall, const float* __restrict__ Hpos,
                const float* __restrict__ rel, float* __restrict__ out) {
    int gid = blockIdx.x * 256 + threadIdx.x;   // 0..4607
    int b = gid / NN, nloc = gid % NN;
    int ntile = nloc >> 4, qq = nloc & 15;
    size_t base = ((size_t)(b * NTILES + ntile) * MSPLIT) * SLICE + qq;
    const float* ha = Hall + base;
    const float* hp = Hpos + base;
    float cumr = 0.f, cumn = 0.f, apn = 0.f, totr = 0.f;
    #pragma unroll
    for (int c = 0; c < 25; ++c) {
        float a = 0.f, r = 0.f;
        #pragma unroll
        for (int s = 0; s < MSPLIT; ++s) {
            a += ha[(size_t)s * SLICE + c * 16];
            r += hp[(size_t)s * SLICE + c * 16];
        }
        cumr += r; cumn += a;
        apn  += (cumr / (1e-16f + cumn)) * r;
        totr += r;
    }
    float ap = apn / totr;                      // totr >= 1 (self-match)
    float rl = rel[gid];
    float loss = 1.0f - (ap * rl + 0.5f * (1.0f - rl));

    for (int off = 32; off > 0; off >>= 1) loss += __shfl_down(loss, off, 64);
    __shared__ float wsum[4];
    int ln = threadIdx.x & 63, wv = threadIdx.x >> 6;
    if (ln == 0) wsum[wv] = loss;
    __syncthreads();
    if (threadIdx.x == 0) {
        float t = wsum[0] + wsum[1] + wsum[2] + wsum[3];
        atomicAdd(out, t * (1.0f / (float)(BB * NN)));
    }
}

extern "C" void kernel_launch(void* const* d_in, const int* in_sizes, int n_in,
                              void* d_out, int out_size, void* d_ws, size_t ws_size,
                              hipStream_t stream) {
    const float* img1 = (const float*)d_in[0];
    const float* img2 = (const float*)d_in[1];
    const float* rel  = (const float*)d_in[2];
    const float* grid = (const float*)d_in[3];

    char* ws = (char*)d_ws;
    const size_t qt_bytes   = (size_t)BB * NN * CC * sizeof(u16);                    // 1.18 MB
    const size_t part_bytes = (size_t)BB * NTILES * MSPLIT * SLICE * sizeof(float);  // 0.96 MB
    u16*   Qt   = (u16*)ws;
    u16*   Dt   = (u16*)(ws + qt_bytes);
    float* Hall = (float*)(ws + 2 * qt_bytes);
    float* Hpos = (float*)(ws + 2 * qt_bytes + part_bytes);

    k_prep    <<<288, 256, 0, stream>>>(img1, img2, grid, Qt, Dt, (float*)d_out);
    k_main    <<<BB * NTILES * MSPLIT, 256, 0, stream>>>(Qt, Dt, Hall, Hpos);
    k_finalize<<<(BB * NN) / 256, 256, 0, stream>>>(Hall, Hpos, rel, (float*)d_out);
}